// Round 2
// baseline (1009.816 us; speedup 1.0000x reference)
//
#include <hip/hip_runtime.h>
#include <math.h>

// SelfResidualVQ on MI355X — round 2 (fp32, algebraic restructuring; blind
// resubmit after two broker timeouts, + GEMM register-prefetch, merged zero).
//
// Key identities:
//   argmax_k( (r/|r|) . cbn_k ) == argmax_k( r . cbn_k )           (scale-invariant)
//   S_{t+1} = S_t - G[idx_t]  where  G = cbn @ cbn^T               (Gram update)
//   ||q - r_t||^2 = 1 - 2*S_t[idx] + rho_t = rho_{t+1}             (commit recurrence)
//   quantized_sum = sum_t cbn[idx_t]                               (gather)
// => one 16384x2048x512 SGEMM + one 2048x2048x512 SGEMM instead of 8 big matmuls.

#define TOKENS 16384
#define DDIM   512
#define NCODE  2048
#define NQ     8
#define CHUNK  4096            // tokens per S-chunk (bounds ws usage ~55 MB)

// ws layout in floats
#define CBN_OFF  0u                       // 2048*512        = 1,048,576
#define G_OFF    1048576u                 // 2048*2048       = 4,194,304
#define S_OFF    5242880u                 // CHUNK*2048      = 8,388,608
#define ACC_OFF  13631488u                // 8 commit accumulators
// total ~13.6M floats = ~54.6 MB of d_ws

// d_out layout in floats (reference return order, flattened):
#define QS_OFF   0u                       // quantized_sum: 16384*512 = 8,388,608
#define IDX_OFF  8388608u                 // all_indices:   16384*8   = 131,072 (as float)
#define CL_OFF   8519680u                 // commit_losses: 8

// ---------------------------------------------------------------------------
__global__ __launch_bounds__(256) void normalize_cb(const float* __restrict__ cb,
                                                    float* __restrict__ cbn,
                                                    float* __restrict__ acc) {
  if (blockIdx.x == 0 && threadIdx.x < NQ) acc[threadIdx.x] = 0.0f;
  int lane = threadIdx.x & 63;
  int wv   = threadIdx.x >> 6;
  int row  = blockIdx.x * 4 + wv;                  // 2048 rows, grid 512
  const float4* rp = (const float4*)(cb + (size_t)row * DDIM);
  float4 a = rp[lane * 2 + 0];
  float4 b = rp[lane * 2 + 1];
  float ss = a.x*a.x + a.y*a.y + a.z*a.z + a.w*a.w
           + b.x*b.x + b.y*b.y + b.z*b.z + b.w*b.w;
  #pragma unroll
  for (int o = 1; o < 64; o <<= 1) ss += __shfl_xor(ss, o);
  float nrm = fmaxf(sqrtf(ss), 1e-12f);            // jnp.clip(norm, 1e-12)
  float4 o0 = make_float4(a.x/nrm, a.y/nrm, a.z/nrm, a.w/nrm);
  float4 o1 = make_float4(b.x/nrm, b.y/nrm, b.z/nrm, b.w/nrm);
  float4* op = (float4*)(cbn + (size_t)row * DDIM);
  op[lane * 2 + 0] = o0;
  op[lane * 2 + 1] = o1;
}

// ---------------------------------------------------------------------------
__global__ void finalize(const float* __restrict__ acc, float* __restrict__ out) {
  if (threadIdx.x < NQ)
    out[CL_OFF + threadIdx.x] = acc[threadIdx.x] * (1.0f / ((float)TOKENS * (float)DDIM));
}

// ---------------------------------------------------------------------------
// C[M x 2048] = A[M x 512] @ B[2048 x 512]^T   (both row-major, "NT")
// 128x128 block tile, BK=16, 256 threads, 8x8 per-thread tile.
// Register-prefetch: next K-tile's global loads issue right after the LDS
// write barrier and hide under the 16x64-FMA compute block.
__global__ __launch_bounds__(256) void gemm_nt(const float* __restrict__ A,
                                               const float* __restrict__ B,
                                               float* __restrict__ C) {
  const int K = DDIM, N = NCODE;
  __shared__ float As[16][128 + 4];
  __shared__ float Bs[16][128 + 4];
  const int bn = blockIdx.x * 128;
  const int bm = blockIdx.y * 128;
  const int t  = threadIdx.x;
  const int tx = t & 15;          // n-tile position
  const int ty = t >> 4;          // m-tile position
  const int lr = t >> 2;          // load row 0..63
  const int lc = (t & 3) * 4;     // load col {0,4,8,12}

  float acc[8][8];
  #pragma unroll
  for (int i = 0; i < 8; ++i)
    #pragma unroll
    for (int j = 0; j < 8; ++j) acc[i][j] = 0.0f;

  const float* Ap = A + (size_t)(bm + lr) * K + lc;
  const float* Bp = B + (size_t)(bn + lr) * K + lc;

  float4 a0 = *(const float4*)(Ap);
  float4 a1 = *(const float4*)(Ap + (size_t)64 * K);
  float4 b0 = *(const float4*)(Bp);
  float4 b1 = *(const float4*)(Bp + (size_t)64 * K);

  for (int k0 = 0; k0 < K; k0 += 16) {
    __syncthreads();                       // previous iter done reading LDS
    As[lc+0][lr] = a0.x; As[lc+1][lr] = a0.y; As[lc+2][lr] = a0.z; As[lc+3][lr] = a0.w;
    As[lc+0][lr+64] = a1.x; As[lc+1][lr+64] = a1.y; As[lc+2][lr+64] = a1.z; As[lc+3][lr+64] = a1.w;
    Bs[lc+0][lr] = b0.x; Bs[lc+1][lr] = b0.y; Bs[lc+2][lr] = b0.z; Bs[lc+3][lr] = b0.w;
    Bs[lc+0][lr+64] = b1.x; Bs[lc+1][lr+64] = b1.y; Bs[lc+2][lr+64] = b1.z; Bs[lc+3][lr+64] = b1.w;
    __syncthreads();
    if (k0 + 16 < K) {                     // prefetch next K-tile into regs
      a0 = *(const float4*)(Ap + k0 + 16);
      a1 = *(const float4*)(Ap + (size_t)64 * K + k0 + 16);
      b0 = *(const float4*)(Bp + k0 + 16);
      b1 = *(const float4*)(Bp + (size_t)64 * K + k0 + 16);
    }
    #pragma unroll
    for (int kk = 0; kk < 16; ++kk) {
      float av[8], bv[8];
      *(float4*)(av + 0) = *(const float4*)&As[kk][ty * 4];
      *(float4*)(av + 4) = *(const float4*)&As[kk][ty * 4 + 64];
      *(float4*)(bv + 0) = *(const float4*)&Bs[kk][tx * 4];
      *(float4*)(bv + 4) = *(const float4*)&Bs[kk][tx * 4 + 64];
      #pragma unroll
      for (int i = 0; i < 8; ++i)
        #pragma unroll
        for (int j = 0; j < 8; ++j) acc[i][j] += av[i] * bv[j];
    }
  }

  #pragma unroll
  for (int i = 0; i < 8; ++i) {
    int m = bm + ty * 4 + (i & 3) + ((i >> 2) << 6);
    float4 v0 = make_float4(acc[i][0], acc[i][1], acc[i][2], acc[i][3]);
    float4 v1 = make_float4(acc[i][4], acc[i][5], acc[i][6], acc[i][7]);
    *(float4*)&C[(size_t)m * N + bn + tx * 4]      = v0;
    *(float4*)&C[(size_t)m * N + bn + tx * 4 + 64] = v1;
  }
}

// ---------------------------------------------------------------------------
// One wave per token: S-row (2048 fp32) lives in 32 VGPRs/lane.
// 8 steps of {wave argmax -> rho update -> idx out -> qsum gather -> S -= G[idx]}.
__global__ __launch_bounds__(256) void vq_steps(const float* __restrict__ S,
                                                const float* __restrict__ G,
                                                const float* __restrict__ cbn,
                                                const float* __restrict__ x,
                                                float* __restrict__ out,
                                                float* __restrict__ acc,
                                                int tok0) {
  const int lane = threadIdx.x & 63;
  const int wv   = threadIdx.x >> 6;
  const int trel = blockIdx.x * 4 + wv;     // token within chunk
  const int tok  = tok0 + trel;

  // load S row: s[q*4+j] holds S[tok][q*256 + lane*4 + j]
  float s[32];
  const float4* sp = (const float4*)(S + (size_t)trel * NCODE);
  #pragma unroll
  for (int q = 0; q < 8; ++q) {
    float4 v = sp[q * 64 + lane];
    s[q*4+0] = v.x; s[q*4+1] = v.y; s[q*4+2] = v.z; s[q*4+3] = v.w;
  }

  // rho_0 = ||x_tok||^2
  const float4* xp = (const float4*)(x + (size_t)tok * DDIM);
  float4 x0 = xp[lane * 2 + 0];
  float4 x1 = xp[lane * 2 + 1];
  float rho = x0.x*x0.x + x0.y*x0.y + x0.z*x0.z + x0.w*x0.w
            + x1.x*x1.x + x1.y*x1.y + x1.z*x1.z + x1.w*x1.w;
  #pragma unroll
  for (int o = 1; o < 64; o <<= 1) rho += __shfl_xor(rho, o);

  float qs[8] = {0.f,0.f,0.f,0.f,0.f,0.f,0.f,0.f};
  __shared__ float cpart[4];

  for (int t = 0; t < NQ; ++t) {
    // lane-local argmax over 32 held entries (ascending c => '>' keeps first)
    float mv = s[0];
    int   mc = lane * 4;
    #pragma unroll
    for (int r = 1; r < 32; ++r) {
      int c = ((r >> 2) << 8) + lane * 4 + (r & 3);
      if (s[r] > mv) { mv = s[r]; mc = c; }
    }
    // cross-lane argmax, smallest index wins ties (match jnp.argmax)
    #pragma unroll
    for (int o = 1; o < 64; o <<= 1) {
      float ov = __shfl_xor(mv, o);
      int   oc = __shfl_xor(mc, o);
      if (ov > mv || (ov == mv && oc < mc)) { mv = ov; mc = oc; }
    }

    rho = rho - 2.0f * mv + 1.0f;           // = ||q - r_t||^2 summed -> rho_{t+1}

    if (lane == 0) cpart[wv] = rho;
    __syncthreads();
    if (threadIdx.x == 0)
      atomicAdd(&acc[t], cpart[0] + cpart[1] + cpart[2] + cpart[3]);
    __syncthreads();

    if (lane == 0) out[IDX_OFF + (size_t)tok * NQ + t] = (float)mc;

    // quantized_sum += cbn[idx]
    const float4* cr = (const float4*)(cbn + (size_t)mc * DDIM);
    float4 c0 = cr[lane * 2 + 0];
    float4 c1 = cr[lane * 2 + 1];
    qs[0]+=c0.x; qs[1]+=c0.y; qs[2]+=c0.z; qs[3]+=c0.w;
    qs[4]+=c1.x; qs[5]+=c1.y; qs[6]+=c1.z; qs[7]+=c1.w;

    if (t < NQ - 1) {
      const float4* gr = (const float4*)(G + (size_t)mc * NCODE);
      #pragma unroll
      for (int q = 0; q < 8; ++q) {
        float4 g = gr[q * 64 + lane];
        s[q*4+0] -= g.x; s[q*4+1] -= g.y; s[q*4+2] -= g.z; s[q*4+3] -= g.w;
      }
    }
  }

  float4* op = (float4*)(out + QS_OFF + (size_t)tok * DDIM);
  op[lane * 2 + 0] = make_float4(qs[0], qs[1], qs[2], qs[3]);
  op[lane * 2 + 1] = make_float4(qs[4], qs[5], qs[6], qs[7]);
}

// ---------------------------------------------------------------------------
extern "C" void kernel_launch(void* const* d_in, const int* in_sizes, int n_in,
                              void* d_out, int out_size, void* d_ws, size_t ws_size,
                              hipStream_t stream) {
  const float* x  = (const float*)d_in[0];   // (1,16384,512) fp32
  const float* cb = (const float*)d_in[1];   // (2048,512) fp32
  float* out = (float*)d_out;
  float* ws  = (float*)d_ws;

  float* cbn = ws + CBN_OFF;
  float* G   = ws + G_OFF;
  float* S   = ws + S_OFF;
  float* acc = ws + ACC_OFF;

  normalize_cb<<<NCODE / 4, 256, 0, stream>>>(cb, cbn, acc);
  // G = cbn @ cbn^T  (2048 x 2048)
  gemm_nt<<<dim3(NCODE / 128, NCODE / 128), 256, 0, stream>>>(cbn, cbn, G);

  for (int c = 0; c < TOKENS / CHUNK; ++c) {
    gemm_nt<<<dim3(NCODE / 128, CHUNK / 128), 256, 0, stream>>>(
        x + (size_t)c * CHUNK * DDIM, cbn, S);
    vq_steps<<<CHUNK / 4, 256, 0, stream>>>(S, G, cbn, x, out, acc, c * CHUNK);
  }

  finalize<<<1, 64, 0, stream>>>(acc, out);
}

// Round 8
// 699.371 us; speedup vs baseline: 1.4439x; 1.4439x over previous
//
#include <hip/hip_runtime.h>
#include <math.h>

// SelfResidualVQ on MI355X — round 8 (= round 3; broker timeouts r3-r7 — this
// code has never executed; only R2 ever ran: 1010us, passed, absmax 1.95e-3).
// R2 post-mortem: vq_steps 4x120us latency-bound (VALUBusy 7%, occ 18%, BW 16%)
//   -> remove per-step barriers, tree argmax, single full-token dispatch.
// GEMM 78 TF (vs ~148 TF issue ceiling; hypotheses: ds_read latency @2 waves/SIMD,
//   operand stalls, barrier lockstep) -> need first GEMM counters to pick fix.
// Queued: bf16x3 split-MFMA S-GEMM (needs exact recheck: ~1.6 expected argmax
//   flips bare => 20-40% pass; recheck machinery too risky to ship untested).
//
// Identities:
//   argmax_k( (r/|r|) . cbn_k ) == argmax_k( r . cbn_k )
//   S_{t+1} = S_t - G[idx_t],  G = cbn @ cbn^T
//   rho_{t+1} = rho_t - 2*S_t[idx] + 1 = ||q - r_t||^2 (summed over d)
//   quantized_sum = sum_t cbn[idx_t]

#define TOKENS 16384
#define DDIM   512
#define NCODE  2048
#define NQ     8
#define CHUNK  4096

// ws layout in floats
#define CBN_OFF  0u            // 2048*512
#define G_OFF    1048576u      // 2048*2048
#define S_OFF    5242880u      // up to TOKENS*2048
#define ACC_FULL (S_OFF + (size_t)TOKENS * NCODE)   // full-path acc
#define ACC_CHNK (S_OFF + (size_t)CHUNK  * NCODE)   // chunked-path acc

// d_out layout in floats:
#define QS_OFF   0u            // quantized_sum: 16384*512
#define IDX_OFF  8388608u      // all_indices:   16384*8 (as float)
#define CL_OFF   8519680u      // commit_losses: 8

// ---------------------------------------------------------------------------
__global__ __launch_bounds__(256) void normalize_cb(const float* __restrict__ cb,
                                                    float* __restrict__ cbn,
                                                    float* __restrict__ acc) {
  if (blockIdx.x == 0 && threadIdx.x < NQ) acc[threadIdx.x] = 0.0f;
  int lane = threadIdx.x & 63;
  int wv   = threadIdx.x >> 6;
  int row  = blockIdx.x * 4 + wv;
  const float4* rp = (const float4*)(cb + (size_t)row * DDIM);
  float4 a = rp[lane * 2 + 0];
  float4 b = rp[lane * 2 + 1];
  float ss = a.x*a.x + a.y*a.y + a.z*a.z + a.w*a.w
           + b.x*b.x + b.y*b.y + b.z*b.z + b.w*b.w;
  #pragma unroll
  for (int o = 1; o < 64; o <<= 1) ss += __shfl_xor(ss, o);
  float nrm = fmaxf(sqrtf(ss), 1e-12f);
  float4 o0 = make_float4(a.x/nrm, a.y/nrm, a.z/nrm, a.w/nrm);
  float4 o1 = make_float4(b.x/nrm, b.y/nrm, b.z/nrm, b.w/nrm);
  float4* op = (float4*)(cbn + (size_t)row * DDIM);
  op[lane * 2 + 0] = o0;
  op[lane * 2 + 1] = o1;
}

// ---------------------------------------------------------------------------
__global__ void finalize(const float* __restrict__ acc, float* __restrict__ out) {
  if (threadIdx.x < NQ)
    out[CL_OFF + threadIdx.x] = acc[threadIdx.x] * (1.0f / ((float)TOKENS * (float)DDIM));
}

// ---------------------------------------------------------------------------
// C[M x 2048] = A[M x 512] @ B[2048 x 512]^T  (row-major, NT)
// 128x128 tile, BK=16, 256 threads, 8x8/thread.
// Single-barrier LDS double-buffer: {write regs->buf; prefetch; barrier; compute}.
// Race-free: iter-(k+2) write to buf[cur] is after barrier k+1; iter-k read of
// buf[cur] is before barrier k+1 (compute ends each loop body).
__global__ __launch_bounds__(256) void gemm_nt(const float* __restrict__ A,
                                               const float* __restrict__ B,
                                               float* __restrict__ C) {
  const int K = DDIM, N = NCODE;
  __shared__ float As[2][16][132];
  __shared__ float Bs[2][16][132];
  const int bn = blockIdx.x * 128;
  const int bm = blockIdx.y * 128;
  const int t  = threadIdx.x;
  const int tx = t & 15;
  const int ty = t >> 4;
  const int lr = t >> 2;
  const int lc = (t & 3) * 4;

  float acc[8][8];
  #pragma unroll
  for (int i = 0; i < 8; ++i)
    #pragma unroll
    for (int j = 0; j < 8; ++j) acc[i][j] = 0.0f;

  const float* Ap = A + (size_t)(bm + lr) * K + lc;
  const float* Bp = B + (size_t)(bn + lr) * K + lc;

  float4 a0 = *(const float4*)(Ap);
  float4 a1 = *(const float4*)(Ap + (size_t)64 * K);
  float4 b0 = *(const float4*)(Bp);
  float4 b1 = *(const float4*)(Bp + (size_t)64 * K);

  int cur = 0;
  for (int k0 = 0; k0 < K; k0 += 16) {
    As[cur][lc+0][lr]    = a0.x; As[cur][lc+1][lr]    = a0.y;
    As[cur][lc+2][lr]    = a0.z; As[cur][lc+3][lr]    = a0.w;
    As[cur][lc+0][lr+64] = a1.x; As[cur][lc+1][lr+64] = a1.y;
    As[cur][lc+2][lr+64] = a1.z; As[cur][lc+3][lr+64] = a1.w;
    Bs[cur][lc+0][lr]    = b0.x; Bs[cur][lc+1][lr]    = b0.y;
    Bs[cur][lc+2][lr]    = b0.z; Bs[cur][lc+3][lr]    = b0.w;
    Bs[cur][lc+0][lr+64] = b1.x; Bs[cur][lc+1][lr+64] = b1.y;
    Bs[cur][lc+2][lr+64] = b1.z; Bs[cur][lc+3][lr+64] = b1.w;
    if (k0 + 16 < K) {                      // prefetch next K-tile into regs
      a0 = *(const float4*)(Ap + k0 + 16);
      a1 = *(const float4*)(Ap + (size_t)64 * K + k0 + 16);
      b0 = *(const float4*)(Bp + k0 + 16);
      b1 = *(const float4*)(Bp + (size_t)64 * K + k0 + 16);
    }
    __syncthreads();                        // writes visible; prev reads done
    #pragma unroll
    for (int kk = 0; kk < 16; ++kk) {
      float av[8], bv[8];
      *(float4*)(av + 0) = *(const float4*)&As[cur][kk][ty * 4];
      *(float4*)(av + 4) = *(const float4*)&As[cur][kk][ty * 4 + 64];
      *(float4*)(bv + 0) = *(const float4*)&Bs[cur][kk][tx * 4];
      *(float4*)(bv + 4) = *(const float4*)&Bs[cur][kk][tx * 4 + 64];
      #pragma unroll
      for (int i = 0; i < 8; ++i)
        #pragma unroll
        for (int j = 0; j < 8; ++j) acc[i][j] += av[i] * bv[j];
    }
    cur ^= 1;
  }

  #pragma unroll
  for (int i = 0; i < 8; ++i) {
    int m = bm + ty * 4 + (i & 3) + ((i >> 2) << 6);
    float4 v0 = make_float4(acc[i][0], acc[i][1], acc[i][2], acc[i][3]);
    float4 v1 = make_float4(acc[i][4], acc[i][5], acc[i][6], acc[i][7]);
    *(float4*)&C[(size_t)m * N + bn + tx * 4]      = v0;
    *(float4*)&C[(size_t)m * N + bn + tx * 4 + 64] = v1;
  }
}

// ---------------------------------------------------------------------------
// One wave per token; S row (2048 fp32) in 32 VGPRs/lane.
// No per-step barriers: waves free-run; commit losses reduced once at end.
__global__ __launch_bounds__(256) void vq_steps(const float* __restrict__ S,
                                                const float* __restrict__ G,
                                                const float* __restrict__ cbn,
                                                const float* __restrict__ x,
                                                float* __restrict__ out,
                                                float* __restrict__ acc,
                                                int tok0) {
  const int lane = threadIdx.x & 63;
  const int wv   = threadIdx.x >> 6;
  const int trel = blockIdx.x * 4 + wv;
  const int tok  = tok0 + trel;

  // s[q*4+j] = S[tok][q*256 + lane*4 + j]  (col monotone in reg index r)
  float s[32];
  const float4* sp = (const float4*)(S + (size_t)trel * NCODE);
  #pragma unroll
  for (int q = 0; q < 8; ++q) {
    float4 v = sp[q * 64 + lane];
    s[q*4+0] = v.x; s[q*4+1] = v.y; s[q*4+2] = v.z; s[q*4+3] = v.w;
  }

  const float4* xp = (const float4*)(x + (size_t)tok * DDIM);
  float4 x0 = xp[lane * 2 + 0];
  float4 x1 = xp[lane * 2 + 1];
  float rho = x0.x*x0.x + x0.y*x0.y + x0.z*x0.z + x0.w*x0.w
            + x1.x*x1.x + x1.y*x1.y + x1.z*x1.z + x1.w*x1.w;
  #pragma unroll
  for (int o = 1; o < 64; o <<= 1) rho += __shfl_xor(rho, o);

  float qs[8] = {0.f,0.f,0.f,0.f,0.f,0.f,0.f,0.f};
  __shared__ float cl[4][NQ];

  for (int t = 0; t < NQ; ++t) {
    // ---- lane-local argmax, depth-5 tree (first-max-wins preserved:
    //      col sets monotone in pair index; strict '>' for later operand)
    float tv[16]; int tc[16];
    #pragma unroll
    for (int r = 0; r < 16; ++r) {
      int ca = ((2*r) >> 2 << 8) + lane * 4 + ((2*r) & 3);
      float va = s[2*r], vb = s[2*r+1];
      bool b = vb > va;
      tv[r] = b ? vb : va;
      tc[r] = b ? ca + 1 : ca;
    }
    #pragma unroll
    for (int h = 8; h >= 1; h >>= 1) {
      #pragma unroll
      for (int r = 0; r < 16; ++r) {
        if (r < h) {
          bool b = tv[r + h] > tv[r];
          tv[r] = b ? tv[r + h] : tv[r];
          tc[r] = b ? tc[r + h] : tc[r];
        }
      }
    }
    float mv = tv[0];
    int   mc = tc[0];
    // ---- cross-lane argmax, smallest index wins ties
    #pragma unroll
    for (int o = 1; o < 64; o <<= 1) {
      float ov = __shfl_xor(mv, o);
      int   oc = __shfl_xor(mc, o);
      if (ov > mv || (ov == mv && oc < mc)) { mv = ov; mc = oc; }
    }

    rho = rho - 2.0f * mv + 1.0f;
    if (lane == 0) {
      cl[wv][t] = rho;
      out[IDX_OFF + (size_t)tok * NQ + t] = (float)mc;
    }

    // quantized_sum += cbn[idx]
    const float4* cr = (const float4*)(cbn + (size_t)mc * DDIM);
    float4 c0 = cr[lane * 2 + 0];
    float4 c1 = cr[lane * 2 + 1];
    qs[0]+=c0.x; qs[1]+=c0.y; qs[2]+=c0.z; qs[3]+=c0.w;
    qs[4]+=c1.x; qs[5]+=c1.y; qs[6]+=c1.z; qs[7]+=c1.w;

    if (t < NQ - 1) {
      const float4* gr = (const float4*)(G + (size_t)mc * NCODE);
      #pragma unroll
      for (int q = 0; q < 8; ++q) {
        float4 g = gr[q * 64 + lane];
        s[q*4+0] -= g.x; s[q*4+1] -= g.y; s[q*4+2] -= g.z; s[q*4+3] -= g.w;
      }
    }
  }

  float4* op = (float4*)(out + QS_OFF + (size_t)tok * DDIM);
  op[lane * 2 + 0] = make_float4(qs[0], qs[1], qs[2], qs[3]);
  op[lane * 2 + 1] = make_float4(qs[4], qs[5], qs[6], qs[7]);

  // ---- once-per-block commit reduction (same add order as R2: wv 0..3)
  __syncthreads();
  if (threadIdx.x < NQ) {
    float v = cl[0][threadIdx.x] + cl[1][threadIdx.x]
            + cl[2][threadIdx.x] + cl[3][threadIdx.x];
    atomicAdd(&acc[threadIdx.x], v);
  }
}

// ---------------------------------------------------------------------------
extern "C" void kernel_launch(void* const* d_in, const int* in_sizes, int n_in,
                              void* d_out, int out_size, void* d_ws, size_t ws_size,
                              hipStream_t stream) {
  const float* x  = (const float*)d_in[0];
  const float* cb = (const float*)d_in[1];
  float* out = (float*)d_out;
  float* ws  = (float*)d_ws;

  float* cbn = ws + CBN_OFF;
  float* G   = ws + G_OFF;
  float* S   = ws + S_OFF;

  const size_t need_full = (ACC_FULL + 16) * sizeof(float);   // ~155 MB
  const bool full = ws_size >= need_full;
  float* acc = ws + (full ? ACC_FULL : ACC_CHNK);

  normalize_cb<<<NCODE / 4, 256, 0, stream>>>(cb, cbn, acc);
  gemm_nt<<<dim3(NCODE / 128, NCODE / 128), 256, 0, stream>>>(cbn, cbn, G);

  if (full) {
    gemm_nt<<<dim3(NCODE / 128, TOKENS / 128), 256, 0, stream>>>(x, cbn, S);
    vq_steps<<<TOKENS / 4, 256, 0, stream>>>(S, G, cbn, x, out, acc, 0);
  } else {
    for (int c = 0; c < TOKENS / CHUNK; ++c) {
      gemm_nt<<<dim3(NCODE / 128, CHUNK / 128), 256, 0, stream>>>(
          x + (size_t)c * CHUNK * DDIM, cbn, S);
      vq_steps<<<CHUNK / 4, 256, 0, stream>>>(S, G, cbn, x, out, acc, c * CHUNK);
    }
  }

  finalize<<<1, 64, 0, stream>>>(acc, out);
}

// Round 11
// 668.867 us; speedup vs baseline: 1.5097x; 1.0456x over previous
//
#include <hip/hip_runtime.h>
#include <math.h>

// SelfResidualVQ on MI355X — round 11 (= round 9 resubmitted; broker timeouts
// r9/r10 — never executed). Audits done across idle rounds: STAGE race-freedom
// + lane-linear global/LDS order match (rule #21 "neither" branch), fragment
// ds_read_b128 bank pattern, k-permutation invariance, recheck bitwise-
// exactness vs the R2/R3-passing fp32 path, ws sizing (92 MB chunked).
// R3 measured: 699us = S-GEMM 406 (84.6 TF fp32, VALUBusy 71%) + Gram ~51 +
//   vq ~230 + misc. fp32 VALU near ceiling -> bf16x3 MFMA (25x pipe headroom).
// G (Gram) stays fp32 gemm_nt — its exactness is required by the recheck.

#define TOKENS 16384
#define DDIM   512
#define NCODE  2048
#define NQ     8
#define CHUNK  4096
#define DTHR   1e-3f

typedef short   bf16x8  __attribute__((ext_vector_type(8)));
typedef float   f32x4   __attribute__((ext_vector_type(4)));
typedef short   s16x8   __attribute__((ext_vector_type(8)));

#define GLOBAL_AS __attribute__((address_space(1)))
#define LDS_AS    __attribute__((address_space(3)))

// ws layout in floats
#define CBN_OFF  0u            // 2048*512                 = 1,048,576
#define G_OFF    1048576u      // 2048*2048                = 4,194,304
#define S_OFF    5242880u      // CHUNK*2048               = 8,388,608
#define XHI_OFF  13631488u     // 16384*512 bf16           = 4,194,304 fl
#define XLO_OFF  17825792u     //                          = 4,194,304 fl
#define BHI_OFF  22020096u     // 2048*512 bf16            =   524,288 fl
#define BLO_OFF  22544384u     //                          =   524,288 fl
#define ACC_OFF  23068672u     // 8 commit accumulators    (~92 MB total)

// d_out layout in floats:
#define QS_OFF   0u            // quantized_sum: 16384*512
#define IDX_OFF  8388608u      // all_indices:   16384*8 (as float)
#define CL_OFF   8519680u      // commit_losses: 8

__device__ inline unsigned short f2bf(float f) {        // RNE fp32->bf16 bits
  unsigned u = __float_as_uint(f);
  return (unsigned short)((u + 0x7FFFu + ((u >> 16) & 1u)) >> 16);
}
__device__ inline float bf2f(unsigned short h) {
  return __uint_as_float(((unsigned)h) << 16);
}

// ---------------------------------------------------------------------------
// Normalize codebook rows; also emit tile-major bf16 hi/lo for MFMA B, zero acc.
// Tile-major granule: [nb][ks][g][r] of 8 bf16; lane k-range = lane*8..+7
//   -> ks = lane>>2, g = lane&3.
__global__ __launch_bounds__(256) void normalize_cb(const float* __restrict__ cb,
                                                    float* __restrict__ cbn,
                                                    short* __restrict__ bhi,
                                                    short* __restrict__ blo,
                                                    float* __restrict__ acc) {
  if (blockIdx.x == 0 && threadIdx.x < NQ) acc[threadIdx.x] = 0.0f;
  int lane = threadIdx.x & 63;
  int wv   = threadIdx.x >> 6;
  int row  = blockIdx.x * 4 + wv;
  const float4* rp = (const float4*)(cb + (size_t)row * DDIM);
  float4 a = rp[lane * 2 + 0];
  float4 b = rp[lane * 2 + 1];
  float ss = a.x*a.x + a.y*a.y + a.z*a.z + a.w*a.w
           + b.x*b.x + b.y*b.y + b.z*b.z + b.w*b.w;
  #pragma unroll
  for (int o = 1; o < 64; o <<= 1) ss += __shfl_xor(ss, o);
  float nrm = fmaxf(sqrtf(ss), 1e-12f);
  float v[8] = {a.x/nrm, a.y/nrm, a.z/nrm, a.w/nrm,
                b.x/nrm, b.y/nrm, b.z/nrm, b.w/nrm};
  float4* op = (float4*)(cbn + (size_t)row * DDIM);
  op[lane*2+0] = make_float4(v[0], v[1], v[2], v[3]);
  op[lane*2+1] = make_float4(v[4], v[5], v[6], v[7]);

  s16x8 h8, l8;
  #pragma unroll
  for (int i = 0; i < 8; ++i) {
    unsigned short h = f2bf(v[i]);
    h8[i] = (short)h;
    l8[i] = (short)f2bf(v[i] - bf2f(h));
  }
  int nb = row >> 7, rr = row & 127, ks = lane >> 2, g = lane & 3;
  size_t gidx = ((size_t)((nb * 16 + ks) * 4 + g) * 128 + rr) * 8;
  *(s16x8*)(bhi + gidx) = h8;
  *(s16x8*)(blo + gidx) = l8;
}

// ---------------------------------------------------------------------------
// x -> tile-major bf16 hi/lo.  granule gid: r=gid&127, g=(gid>>7)&3,
// ks=(gid>>9)&15, mb=gid>>13.  1,048,576 granules; grid 4096 x 256.
__global__ __launch_bounds__(256) void split_x(const float* __restrict__ x,
                                               short* __restrict__ xhi,
                                               short* __restrict__ xlo) {
  int gid = blockIdx.x * 256 + threadIdx.x;
  int r  = gid & 127;
  int g  = (gid >> 7) & 3;
  int ks = (gid >> 9) & 15;
  int mb = gid >> 13;
  const float4* src = (const float4*)(x + (size_t)(mb * 128 + r) * DDIM + ks * 32 + g * 8);
  float4 v0 = src[0], v1 = src[1];
  float v[8] = {v0.x, v0.y, v0.z, v0.w, v1.x, v1.y, v1.z, v1.w};
  s16x8 h8, l8;
  #pragma unroll
  for (int i = 0; i < 8; ++i) {
    unsigned short h = f2bf(v[i]);
    h8[i] = (short)h;
    l8[i] = (short)f2bf(v[i] - bf2f(h));
  }
  *(s16x8*)(xhi + (size_t)gid * 8) = h8;
  *(s16x8*)(xlo + (size_t)gid * 8) = l8;
}

// ---------------------------------------------------------------------------
__global__ void finalize(const float* __restrict__ acc, float* __restrict__ out) {
  if (threadIdx.x < NQ)
    out[CL_OFF + threadIdx.x] = acc[threadIdx.x] * (1.0f / ((float)TOKENS * (float)DDIM));
}

// ---------------------------------------------------------------------------
// fp32 Gram GEMM (UNCHANGED arithmetic — G exactness feeds the recheck).
__global__ __launch_bounds__(256) void gemm_nt(const float* __restrict__ A,
                                               const float* __restrict__ B,
                                               float* __restrict__ C) {
  const int K = DDIM, N = NCODE;
  __shared__ float As[2][16][132];
  __shared__ float Bs[2][16][132];
  const int bn = blockIdx.x * 128;
  const int bm = blockIdx.y * 128;
  const int t  = threadIdx.x;
  const int tx = t & 15;
  const int ty = t >> 4;
  const int lr = t >> 2;
  const int lc = (t & 3) * 4;

  float acc[8][8];
  #pragma unroll
  for (int i = 0; i < 8; ++i)
    #pragma unroll
    for (int j = 0; j < 8; ++j) acc[i][j] = 0.0f;

  const float* Ap = A + (size_t)(bm + lr) * K + lc;
  const float* Bp = B + (size_t)(bn + lr) * K + lc;

  float4 a0 = *(const float4*)(Ap);
  float4 a1 = *(const float4*)(Ap + (size_t)64 * K);
  float4 b0 = *(const float4*)(Bp);
  float4 b1 = *(const float4*)(Bp + (size_t)64 * K);

  int cur = 0;
  for (int k0 = 0; k0 < K; k0 += 16) {
    As[cur][lc+0][lr]    = a0.x; As[cur][lc+1][lr]    = a0.y;
    As[cur][lc+2][lr]    = a0.z; As[cur][lc+3][lr]    = a0.w;
    As[cur][lc+0][lr+64] = a1.x; As[cur][lc+1][lr+64] = a1.y;
    As[cur][lc+2][lr+64] = a1.z; As[cur][lc+3][lr+64] = a1.w;
    Bs[cur][lc+0][lr]    = b0.x; Bs[cur][lc+1][lr]    = b0.y;
    Bs[cur][lc+2][lr]    = b0.z; Bs[cur][lc+3][lr]    = b0.w;
    Bs[cur][lc+0][lr+64] = b1.x; Bs[cur][lc+1][lr+64] = b1.y;
    Bs[cur][lc+2][lr+64] = b1.z; Bs[cur][lc+3][lr+64] = b1.w;
    if (k0 + 16 < K) {
      a0 = *(const float4*)(Ap + k0 + 16);
      a1 = *(const float4*)(Ap + (size_t)64 * K + k0 + 16);
      b0 = *(const float4*)(Bp + k0 + 16);
      b1 = *(const float4*)(Bp + (size_t)64 * K + k0 + 16);
    }
    __syncthreads();
    #pragma unroll
    for (int kk = 0; kk < 16; ++kk) {
      float av[8], bv[8];
      *(float4*)(av + 0) = *(const float4*)&As[cur][kk][ty * 4];
      *(float4*)(av + 4) = *(const float4*)&As[cur][kk][ty * 4 + 64];
      *(float4*)(bv + 0) = *(const float4*)&Bs[cur][kk][tx * 4];
      *(float4*)(bv + 4) = *(const float4*)&Bs[cur][kk][tx * 4 + 64];
      #pragma unroll
      for (int i = 0; i < 8; ++i)
        #pragma unroll
        for (int j = 0; j < 8; ++j) acc[i][j] += av[i] * bv[j];
    }
    cur ^= 1;
  }

  #pragma unroll
  for (int i = 0; i < 8; ++i) {
    int m = bm + ty * 4 + (i & 3) + ((i >> 2) << 6);
    float4 v0 = make_float4(acc[i][0], acc[i][1], acc[i][2], acc[i][3]);
    float4 v1 = make_float4(acc[i][4], acc[i][5], acc[i][6], acc[i][7]);
    *(float4*)&C[(size_t)m * N + bn + tx * 4]      = v0;
    *(float4*)&C[(size_t)m * N + bn + tx * 4 + 64] = v1;
  }
}

// ---------------------------------------------------------------------------
// bf16x3 MFMA S-GEMM: S[chunk 4096 x 2048] = x . cbn^T  (approx, err ~5e-6).
// 128x128 tile, BK=32, 4 waves (2x2), 4x4 16x16x32 frags/wave, 3 MFMA/frag-pair.
// LDS 64 KB: double-buffered {Ahi,Alo,Bhi,Blo} 8 KB tiles, global_load_lds w16.
__global__ __launch_bounds__(256) void mfma_s(const short* __restrict__ xhi,
                                              const short* __restrict__ xlo,
                                              const short* __restrict__ bhi,
                                              const short* __restrict__ blo,
                                              float* __restrict__ S, int mb0) {
  __shared__ short lds[2][4][4096];           // 65536 B
  const int l  = threadIdx.x & 63;
  const int w  = threadIdx.x >> 6;
  const int wm = w >> 1, wn = w & 1;
  const int MB = mb0 + blockIdx.y;            // global m-block (x tiles)
  const int NB = blockIdx.x;                  // n-block (codebook tiles)

  const short* src = (w == 0) ? xhi : (w == 1) ? xlo : (w == 2) ? bhi : blo;
  const size_t tb  = (size_t)(((w < 2 ? MB : NB) * 16)) * 4096;  // + ks*4096

  f32x4 acc[4][4];
  #pragma unroll
  for (int i = 0; i < 4; ++i)
    #pragma unroll
    for (int j = 0; j < 4; ++j)
      acc[i][j] = (f32x4){0.f, 0.f, 0.f, 0.f};

  // stage: wave w loads its tile (8 chunks x 1KB) for K-step ks into buf
  #define STAGE(buf, ks)                                                        \
    {                                                                           \
      const short* gsrc = src + tb + (size_t)(ks) * 4096 + l * 8;               \
      short* ldst = &lds[buf][w][0];                                            \
      _Pragma("unroll")                                                         \
      for (int c = 0; c < 8; ++c)                                               \
        __builtin_amdgcn_global_load_lds(                                       \
            (GLOBAL_AS const unsigned int*)(gsrc + c * 512),                    \
            (LDS_AS unsigned int*)(ldst + c * 512), 16, 0, 0);                  \
    }

  STAGE(0, 0);
  const int g = l >> 4, c16 = l & 15;
  for (int ks = 0; ks < 16; ++ks) {
    const int cur = ks & 1;
    __syncthreads();                          // vmcnt(0)+barrier: buf[cur] ready
    if (ks < 15) STAGE(cur ^ 1, ks + 1);      // async prefetch next K-step
    bf16x8 ah[4], al[4], bh[4], bl[4];
    #pragma unroll
    for (int f = 0; f < 4; ++f) {
      int ar = (g * 128 + (wm * 64 + f * 16 + c16)) * 8;
      int br = (g * 128 + (wn * 64 + f * 16 + c16)) * 8;
      ah[f] = *(const bf16x8*)&lds[cur][0][ar];
      al[f] = *(const bf16x8*)&lds[cur][1][ar];
      bh[f] = *(const bf16x8*)&lds[cur][2][br];
      bl[f] = *(const bf16x8*)&lds[cur][3][br];
    }
    #pragma unroll
    for (int fm = 0; fm < 4; ++fm)
      #pragma unroll
      for (int fn = 0; fn < 4; ++fn) {
        acc[fm][fn] = __builtin_amdgcn_mfma_f32_16x16x32_bf16(ah[fm], bh[fn], acc[fm][fn], 0, 0, 0);
        acc[fm][fn] = __builtin_amdgcn_mfma_f32_16x16x32_bf16(ah[fm], bl[fn], acc[fm][fn], 0, 0, 0);
        acc[fm][fn] = __builtin_amdgcn_mfma_f32_16x16x32_bf16(al[fm], bh[fn], acc[fm][fn], 0, 0, 0);
      }
  }
  #undef STAGE

  // C/D layout (m89-verified): col = lane&15, row = (lane>>4)*4 + reg
  #pragma unroll
  for (int fm = 0; fm < 4; ++fm)
    #pragma unroll
    for (int fn = 0; fn < 4; ++fn)
      #pragma unroll
      for (int reg = 0; reg < 4; ++reg) {
        int m = blockIdx.y * 128 + wm * 64 + fm * 16 + g * 4 + reg;
        int n = NB * 128 + wn * 64 + fn * 16 + c16;
        S[(size_t)m * NCODE + n] = acc[fm][fn][reg];
      }
}

// ---------------------------------------------------------------------------
// One wave per token; approx S row in 32 VGPRs; barrier-free across steps.
// Thin-gap (<DTHR) argmaxes re-resolved with a BITWISE reproduction of the
// R2/R3 fp32 path: serial fmac over k ascending, minus fp32 G rows in order.
__global__ __launch_bounds__(256) void vq_steps(const float* __restrict__ S,
                                                const float* __restrict__ G,
                                                const float* __restrict__ cbn,
                                                const float* __restrict__ x,
                                                float* __restrict__ out,
                                                float* __restrict__ acc,
                                                int tok0) {
  const int lane = threadIdx.x & 63;
  const int wv   = threadIdx.x >> 6;
  const int trel = blockIdx.x * 4 + wv;
  const int tok  = tok0 + trel;

  float s[32];
  const float4* sp = (const float4*)(S + (size_t)trel * NCODE);
  #pragma unroll
  for (int q = 0; q < 8; ++q) {
    float4 v = sp[q * 64 + lane];
    s[q*4+0] = v.x; s[q*4+1] = v.y; s[q*4+2] = v.z; s[q*4+3] = v.w;
  }

  const float4* xp = (const float4*)(x + (size_t)tok * DDIM);
  float4 x0 = xp[lane * 2 + 0];
  float4 x1 = xp[lane * 2 + 1];
  float rho = x0.x*x0.x + x0.y*x0.y + x0.z*x0.z + x0.w*x0.w
            + x1.x*x1.x + x1.y*x1.y + x1.z*x1.z + x1.w*x1.w;
  #pragma unroll
  for (int o = 1; o < 64; o <<= 1) rho += __shfl_xor(rho, o);

  float qs[8] = {0.f,0.f,0.f,0.f,0.f,0.f,0.f,0.f};
  __shared__ float cl[4][NQ];
  int i0=0,i1=0,i2=0,i3=0,i4=0,i5=0,i6=0;     // chosen-index history (uniform)

  for (int t = 0; t < NQ; ++t) {
    // lane-local argmax, depth-5 tree (first-max-wins preserved)
    float tv[16]; int tc[16];
    #pragma unroll
    for (int r = 0; r < 16; ++r) {
      int ca = ((2*r) >> 2 << 8) + lane * 4 + ((2*r) & 3);
      float va = s[2*r], vb = s[2*r+1];
      bool b = vb > va;
      tv[r] = b ? vb : va;
      tc[r] = b ? ca + 1 : ca;
    }
    #pragma unroll
    for (int h = 8; h >= 1; h >>= 1) {
      #pragma unroll
      for (int r = 0; r < 16; ++r) {
        if (r < h) {
          bool b = tv[r + h] > tv[r];
          tv[r] = b ? tv[r + h] : tv[r];
          tc[r] = b ? tc[r + h] : tc[r];
        }
      }
    }
    float mv = tv[0];
    int   mc = tc[0];
    #pragma unroll
    for (int o = 1; o < 64; o <<= 1) {
      float ov = __shfl_xor(mv, o);
      int   oc = __shfl_xor(mc, o);
      if (ov > mv || (ov == mv && oc < mc)) { mv = ov; mc = oc; }
    }

    // ---- thin-gap recheck (rare: ~0.5% of token-steps) ----
    int cloc = 0;
    #pragma unroll
    for (int r = 0; r < 32; ++r) cloc += (s[r] >= mv - DTHR) ? 1 : 0;
    #pragma unroll
    for (int o = 1; o < 64; o <<= 1) cloc += __shfl_xor(cloc, o);
    if (cloc > 1) {
      float bv = -3.4e38f; int bc = 0x7FFFFFFF; int seen = 0;
      for (int r = 0; r < 32 && seen < 64; ++r) {
        unsigned long long mask = __ballot(s[r] >= mv - DTHR);
        while (mask && seen < 64) {
          int L = __ffsll((unsigned long long)mask) - 1;
          mask &= mask - 1;
          int kc = ((r >> 2) << 8) + L * 4 + (r & 3);
          if (lane == seen) {
            float e = 0.f;
            const float* xr = x + (size_t)tok * DDIM;
            const float* cr = cbn + (size_t)kc * DDIM;
            for (int k = 0; k < DDIM; ++k) e = fmaf(xr[k], cr[k], e);
            if (t > 0) e -= G[(size_t)i0 * NCODE + kc];
            if (t > 1) e -= G[(size_t)i1 * NCODE + kc];
            if (t > 2) e -= G[(size_t)i2 * NCODE + kc];
            if (t > 3) e -= G[(size_t)i3 * NCODE + kc];
            if (t > 4) e -= G[(size_t)i4 * NCODE + kc];
            if (t > 5) e -= G[(size_t)i5 * NCODE + kc];
            if (t > 6) e -= G[(size_t)i6 * NCODE + kc];
            bv = e; bc = kc;
          }
          ++seen;
        }
      }
      #pragma unroll
      for (int o = 1; o < 64; o <<= 1) {
        float ov = __shfl_xor(bv, o);
        int   oc = __shfl_xor(bc, o);
        if (ov > bv || (ov == bv && oc < bc)) { bv = ov; bc = oc; }
      }
      mv = bv; mc = bc;                       // exact value + index
    }

    // history (mc is wave-uniform)
    if (t == 0) i0 = mc; else if (t == 1) i1 = mc; else if (t == 2) i2 = mc;
    else if (t == 3) i3 = mc; else if (t == 4) i4 = mc; else if (t == 5) i5 = mc;
    else if (t == 6) i6 = mc;

    rho = rho - 2.0f * mv + 1.0f;
    if (lane == 0) {
      cl[wv][t] = rho;
      out[IDX_OFF + (size_t)tok * NQ + t] = (float)mc;
    }

    const float4* cr = (const float4*)(cbn + (size_t)mc * DDIM);
    float4 c0 = cr[lane * 2 + 0];
    float4 c1 = cr[lane * 2 + 1];
    qs[0]+=c0.x; qs[1]+=c0.y; qs[2]+=c0.z; qs[3]+=c0.w;
    qs[4]+=c1.x; qs[5]+=c1.y; qs[6]+=c1.z; qs[7]+=c1.w;

    if (t < NQ - 1) {
      const float4* gr = (const float4*)(G + (size_t)mc * NCODE);
      #pragma unroll
      for (int q = 0; q < 8; ++q) {
        float4 gv = gr[q * 64 + lane];
        s[q*4+0] -= gv.x; s[q*4+1] -= gv.y; s[q*4+2] -= gv.z; s[q*4+3] -= gv.w;
      }
    }
  }

  float4* op = (float4*)(out + QS_OFF + (size_t)tok * DDIM);
  op[lane * 2 + 0] = make_float4(qs[0], qs[1], qs[2], qs[3]);
  op[lane * 2 + 1] = make_float4(qs[4], qs[5], qs[6], qs[7]);

  __syncthreads();
  if (threadIdx.x < NQ) {
    float v = cl[0][threadIdx.x] + cl[1][threadIdx.x]
            + cl[2][threadIdx.x] + cl[3][threadIdx.x];
    atomicAdd(&acc[threadIdx.x], v);
  }
}

// ---------------------------------------------------------------------------
extern "C" void kernel_launch(void* const* d_in, const int* in_sizes, int n_in,
                              void* d_out, int out_size, void* d_ws, size_t ws_size,
                              hipStream_t stream) {
  const float* x  = (const float*)d_in[0];
  const float* cb = (const float*)d_in[1];
  float* out = (float*)d_out;
  float* ws  = (float*)d_ws;

  float* cbn = ws + CBN_OFF;
  float* G   = ws + G_OFF;
  float* S   = ws + S_OFF;
  short* xhi = (short*)(ws + XHI_OFF);
  short* xlo = (short*)(ws + XLO_OFF);
  short* bhi = (short*)(ws + BHI_OFF);
  short* blo = (short*)(ws + BLO_OFF);
  float* acc = ws + ACC_OFF;

  normalize_cb<<<NCODE / 4, 256, 0, stream>>>(cb, cbn, bhi, blo, acc);
  split_x<<<4096, 256, 0, stream>>>(x, xhi, xlo);
  gemm_nt<<<dim3(NCODE / 128, NCODE / 128), 256, 0, stream>>>(cbn, cbn, G);

  for (int c = 0; c < TOKENS / CHUNK; ++c) {
    mfma_s<<<dim3(NCODE / 128, CHUNK / 128), 256, 0, stream>>>(
        xhi, xlo, bhi, blo, S, c * (CHUNK / 128));
    vq_steps<<<CHUNK / 4, 256, 0, stream>>>(S, G, cbn, x, out, acc, c * CHUNK);
  }

  finalize<<<1, 64, 0, stream>>>(acc, out);
}